// Round 3
// baseline (393.280 us; speedup 1.0000x reference)
//
#include <hip/hip_runtime.h>
#include <cstdint>

// Problem constants (from reference): B=8192, DIN=DOUT=4096, NC=64
#define BB   8192
#define DIN  4096
#define DOUT 4096
#define NCL  64

typedef __bf16 bf16;
typedef __attribute__((ext_vector_type(8))) __bf16 bf16x8;
typedef __attribute__((ext_vector_type(4))) float   f32x4;

#define GAS(p) (reinterpret_cast<uint32_t __attribute__((address_space(1)))*>(reinterpret_cast<uintptr_t>(p)))
#define LAS(p) (reinterpret_cast<uint32_t __attribute__((address_space(3)))*>(reinterpret_cast<uintptr_t>(p)))

#define WAITV(n)  asm volatile("s_waitcnt vmcnt(" #n ")" ::: "memory")
#define WAITLN(n) asm volatile("s_waitcnt lgkmcnt(" #n ")" ::: "memory")
#define BARR()    __builtin_amdgcn_s_barrier()
#define SCHED0()  __builtin_amdgcn_sched_barrier(0)
#define MFMA(a, b, c) __builtin_amdgcn_mfma_f32_16x16x32_bf16((a), (b), (c), 0, 0, 0)

// ---------------------------------------------------------------------------
// Kernel 1: prologue (unchanged — verified correct, ~BW-bound).
// tmpL = cluster@style_L, tmpR = cluster@style_R (K=NC=64 via MFMA);
// writes A' = bf16(x*tmpL) and tR = bf16(tmpR).
// ---------------------------------------------------------------------------
__global__ __launch_bounds__(256) void prologue_kernel(
    const float* __restrict__ x, const float* __restrict__ cl,
    const float* __restrict__ sL, const float* __restrict__ sR,
    bf16* __restrict__ Ap, bf16* __restrict__ tR)
{
    __shared__ uint4 lds_u4[3072]; // 48 KiB
    char* lds = (char*)lds_u4;
    const int t    = threadIdx.x;
    const int lane = t & 63;
    const int w    = t >> 6;
    const int wm   = w >> 1, wn = w & 1;
    const int r0   = blockIdx.x * 128;
    const int c0   = blockIdx.y * 128;

    #pragma unroll
    for (int i = 0; i < 4; i++) {
        int tk  = t + i * 256;
        int row = tk >> 3, ch = tk & 7;
        const float* src = cl + (size_t)(r0 + row) * NCL + ch * 8;
        float4 v0 = *(const float4*)src;
        float4 v1 = *(const float4*)(src + 4);
        bf16x8 pk;
        pk[0]=(bf16)v0.x; pk[1]=(bf16)v0.y; pk[2]=(bf16)v0.z; pk[3]=(bf16)v0.w;
        pk[4]=(bf16)v1.x; pk[5]=(bf16)v1.y; pk[6]=(bf16)v1.z; pk[7]=(bf16)v1.w;
        *(bf16x8*)(lds + row * 128 + ((ch ^ (row & 7)) << 4)) = pk;
    }
    #pragma unroll
    for (int i = 0; i < 4; i++) {
        int tk = t + i * 256;
        int n  = tk & 127, c = tk >> 7;
        bf16x8 pl, pr;
        #pragma unroll
        for (int j = 0; j < 8; j++) {
            pl[j] = (bf16)sL[(size_t)(c * 8 + j) * DIN  + c0 + n];
            pr[j] = (bf16)sR[(size_t)(c * 8 + j) * DOUT + c0 + n];
        }
        int off = n * 128 + ((c ^ (n & 7)) << 4);
        *(bf16x8*)(lds + 16384 + off) = pl;
        *(bf16x8*)(lds + 32768 + off) = pr;
    }
    __syncthreads();

    f32x4 accL[4][4] = {};
    f32x4 accR[4][4] = {};
    #pragma unroll
    for (int s = 0; s < 2; s++) {
        bf16x8 a[4], bl[4], br[4];
        #pragma unroll
        for (int m = 0; m < 4; m++) {
            int row = wm * 64 + m * 16 + (lane & 15);
            int ch  = s * 4 + (lane >> 4);
            a[m] = *(bf16x8*)(lds + row * 128 + ((ch ^ (row & 7)) << 4));
        }
        #pragma unroll
        for (int n = 0; n < 4; n++) {
            int row = wn * 64 + n * 16 + (lane & 15);
            int ch  = s * 4 + (lane >> 4);
            int off = row * 128 + ((ch ^ (row & 7)) << 4);
            bl[n] = *(bf16x8*)(lds + 16384 + off);
            br[n] = *(bf16x8*)(lds + 32768 + off);
        }
        #pragma unroll
        for (int m = 0; m < 4; m++)
            #pragma unroll
            for (int n = 0; n < 4; n++) {
                accL[m][n] = MFMA(a[m], bl[n], accL[m][n]);
                accR[m][n] = MFMA(a[m], br[n], accR[m][n]);
            }
    }

    #pragma unroll
    for (int m = 0; m < 4; m++) {
        int rbase = r0 + wm * 64 + m * 16 + ((lane >> 4) << 2);
        #pragma unroll
        for (int n = 0; n < 4; n++) {
            int col = c0 + wn * 64 + n * 16 + (lane & 15);
            #pragma unroll
            for (int j = 0; j < 4; j++) {
                size_t idx = (size_t)(rbase + j) * DIN + col;
                Ap[idx] = (bf16)(x[idx] * accL[m][n][j]);
                tR[idx] = (bf16)accR[m][n][j];
            }
        }
    }
}

// ---------------------------------------------------------------------------
// Kernel 2: W (DIN x DOUT f32) -> Wt (DOUT x DIN bf16)  (unchanged)
// ---------------------------------------------------------------------------
__global__ __launch_bounds__(256) void transpose_kernel(
    const float* __restrict__ W, bf16* __restrict__ Wt)
{
    const int t  = threadIdx.x;
    const int n  = blockIdx.x * 256 + t;
    const int k0 = blockIdx.y * 32;
    bf16x8 v[4];
    #pragma unroll
    for (int q = 0; q < 4; q++)
        #pragma unroll
        for (int j = 0; j < 8; j++)
            v[q][j] = (bf16)W[(size_t)(k0 + q * 8 + j) * DOUT + n];
    bf16* dst = Wt + (size_t)n * DIN + k0;
    #pragma unroll
    for (int q = 0; q < 4; q++)
        *(bf16x8*)(dst + q * 8) = v[q];
}

// ---------------------------------------------------------------------------
// Kernel 3: 256x256 8-phase GEMM with one-phase-ahead ds_read pipelining.
// 512 thr = 8 waves (2M x 4N). BK=64. LDS 128 KiB = 2 buf x 64 KiB
//   {Ah0@0, Ah1@16K, Bh0@32K, Bh1@48K}, 16 KiB pieces.
// Wave row/col remap (so quad0 always lives in the P4-staged piece):
//   wave wm owns A rows {wm*64..+63} (quad0, piece Ah0) u {128+wm*64..} (quad1, Ah1)
//   wave wn owns B cols {wn*32..+31} (b0, Bh0)          u {128+wn*32..} (b1, Bh1)
// Per tile t (CB = buf[t&1], OB = other):
//   P1: ds_read a1 (8, CB.Ah1); stage (t+1).Ah1->OB; vmcnt(6); BAR;
//       lgkm(8); MFMA Q00 (a0*b0 -> acc[0..3][0..1]); BAR
//   P2: ds_read b1 (4, CB.Bh1); stage (t+2).Bh0->CB; vmcnt(6); BAR;
//       lgkm(4); MFMA Q10 (a1*b0 -> acc[4..7][0..1]); BAR
//   P3: lgkm(0); ds_read b0' (4, OB.Bh0); stage (t+2).Bh1->CB; vmcnt(6); BAR;
//       lgkm(4); MFMA Q01 (a0*b1 -> acc[0..3][2..3]); BAR
//   P4: ds_read a0' (8, OB.Ah0); stage (t+2).Ah0->CB; vmcnt(6); BAR;
//       lgkm(12); MFMA Q11 (a1*b1 -> acc[4..7][2..3]); BAR
// Every lgkm wait drains only reads issued >=1 phase earlier (LDS fully
// overlaps MFMA); every vmcnt(6) lands exactly the piece read 2 phases later.
// ---------------------------------------------------------------------------
template<int CUR>
__device__ __forceinline__ void tile_step(char* lds, int tid,
    const bf16* pA1, const bf16* pA2, const bf16* pA3, const bf16* pA4,
    const bf16* pB1, const bf16* pB2, const bf16* pB3, const bf16* pB4,
    int kA1, int kA2, int wm8, int wn4, int sw0, int sw1,
    bf16x8 a0[4][2], bf16x8 a1[4][2], bf16x8 b0[2][2], bf16x8 b1[2][2],
    f32x4 acc[8][4])
{
    constexpr int CB = CUR * 65536;
    constexpr int OB = (CUR ^ 1) * 65536;

    // ---------- P1 ----------
    #pragma unroll
    for (int m = 0; m < 4; m++) {
        a1[m][0] = *(const bf16x8*)(lds + CB + 16384 + wm8 + m * 2048 + sw0);
        a1[m][1] = *(const bf16x8*)(lds + CB + 16384 + wm8 + m * 2048 + sw1);
    }
    __builtin_amdgcn_global_load_lds(GAS(pA3 + kA1), LAS(lds + OB + 16384 + tid * 16), 16, 0, 0);
    __builtin_amdgcn_global_load_lds(GAS(pA4 + kA1), LAS(lds + OB + 24576 + tid * 16), 16, 0, 0);
    WAITV(6);
    BARR();
    WAITLN(8); SCHED0();
    __builtin_amdgcn_s_setprio(1);
    #pragma unroll
    for (int m = 0; m < 4; m++)
        #pragma unroll
        for (int n = 0; n < 2; n++) {
            acc[m][n] = MFMA(a0[m][0], b0[n][0], acc[m][n]);
            acc[m][n] = MFMA(a0[m][1], b0[n][1], acc[m][n]);
        }
    __builtin_amdgcn_s_setprio(0);
    BARR();

    // ---------- P2 ----------
    #pragma unroll
    for (int n = 0; n < 2; n++) {
        b1[n][0] = *(const bf16x8*)(lds + CB + 49152 + wn4 + n * 2048 + sw0);
        b1[n][1] = *(const bf16x8*)(lds + CB + 49152 + wn4 + n * 2048 + sw1);
    }
    __builtin_amdgcn_global_load_lds(GAS(pB1 + kA2), LAS(lds + CB + 32768 + tid * 16), 16, 0, 0);
    __builtin_amdgcn_global_load_lds(GAS(pB2 + kA2), LAS(lds + CB + 40960 + tid * 16), 16, 0, 0);
    WAITV(6);
    BARR();
    WAITLN(4); SCHED0();
    __builtin_amdgcn_s_setprio(1);
    #pragma unroll
    for (int m = 0; m < 4; m++)
        #pragma unroll
        for (int n = 0; n < 2; n++) {
            acc[4 + m][n] = MFMA(a1[m][0], b0[n][0], acc[4 + m][n]);
            acc[4 + m][n] = MFMA(a1[m][1], b0[n][1], acc[4 + m][n]);
        }
    __builtin_amdgcn_s_setprio(0);
    BARR();

    // ---------- P3 ----------
    WAITLN(0);   // drain P2's b1 reads before re-staging Bh1 (race-free by construction)
    #pragma unroll
    for (int n = 0; n < 2; n++) {
        b0[n][0] = *(const bf16x8*)(lds + OB + 32768 + wn4 + n * 2048 + sw0);
        b0[n][1] = *(const bf16x8*)(lds + OB + 32768 + wn4 + n * 2048 + sw1);
    }
    __builtin_amdgcn_global_load_lds(GAS(pB3 + kA2), LAS(lds + CB + 49152 + tid * 16), 16, 0, 0);
    __builtin_amdgcn_global_load_lds(GAS(pB4 + kA2), LAS(lds + CB + 57344 + tid * 16), 16, 0, 0);
    WAITV(6);
    BARR();
    WAITLN(4); SCHED0();
    __builtin_amdgcn_s_setprio(1);
    #pragma unroll
    for (int m = 0; m < 4; m++)
        #pragma unroll
        for (int n = 0; n < 2; n++) {
            acc[m][2 + n] = MFMA(a0[m][0], b1[n][0], acc[m][2 + n]);
            acc[m][2 + n] = MFMA(a0[m][1], b1[n][1], acc[m][2 + n]);
        }
    __builtin_amdgcn_s_setprio(0);
    BARR();

    // ---------- P4 ----------
    #pragma unroll
    for (int m = 0; m < 4; m++) {
        a0[m][0] = *(const bf16x8*)(lds + OB + wm8 + m * 2048 + sw0);
        a0[m][1] = *(const bf16x8*)(lds + OB + wm8 + m * 2048 + sw1);
    }
    __builtin_amdgcn_global_load_lds(GAS(pA1 + kA2), LAS(lds + CB + tid * 16), 16, 0, 0);
    __builtin_amdgcn_global_load_lds(GAS(pA2 + kA2), LAS(lds + CB + 8192 + tid * 16), 16, 0, 0);
    WAITV(6);
    BARR();
    WAITLN(12); SCHED0();
    __builtin_amdgcn_s_setprio(1);
    #pragma unroll
    for (int m = 0; m < 4; m++)
        #pragma unroll
        for (int n = 0; n < 2; n++) {
            acc[4 + m][2 + n] = MFMA(a1[m][0], b1[n][0], acc[4 + m][2 + n]);
            acc[4 + m][2 + n] = MFMA(a1[m][1], b1[n][1], acc[4 + m][2 + n]);
        }
    __builtin_amdgcn_s_setprio(0);
    BARR();
}

__global__ __launch_bounds__(512, 2) void gemm_kernel(
    const bf16* __restrict__ Ap, const bf16* __restrict__ Wt,
    const bf16* __restrict__ tR, float* __restrict__ out)
{
    __shared__ uint4 smem[8192]; // 128 KiB
    char* lds = (char*)smem;
    const int tid  = threadIdx.x;
    const int lane = tid & 63;
    const int w    = tid >> 6;
    const int wm   = w >> 2;   // 0..1
    const int wn   = w & 3;    // 0..3
    const int L = lane & 15, H = lane >> 4;

    // XCD-bijective swizzle: 512 blocks, 8 XCDs, 64 tiles each (4 mt x 16 nt)
    const int bid = blockIdx.x;
    const int xc  = bid & 7, ii = bid >> 3;
    const int mt  = xc * 4 + (ii >> 4);
    const int nt  = ii & 15;
    const size_t brow = (size_t)mt * 256;
    const size_t bcol = (size_t)nt * 256;

    // staging: dest linear (tid*16), source chunk inverse-swizzled
    const int r1  = tid >> 3;
    const int gch = (tid & 7) ^ (r1 & 7);
    const bf16* pA1 = Ap + (brow + r1) * (size_t)DIN + gch * 8;
    const bf16* pA2 = pA1 + (size_t)64  * DIN;
    const bf16* pA3 = pA1 + (size_t)128 * DIN;
    const bf16* pA4 = pA1 + (size_t)192 * DIN;
    const bf16* pB1 = Wt + (bcol + r1) * (size_t)DIN + gch * 8;
    const bf16* pB2 = pB1 + (size_t)64  * DIN;
    const bf16* pB3 = pB1 + (size_t)128 * DIN;
    const bf16* pB4 = pB1 + (size_t)192 * DIN;

    // fragment ds_read lane offsets: row-part L*128, chunk = kk*4+H, slot = chunk^(L&7)
    const int sw0 = L * 128 + ((H ^ (L & 7)) << 4);
    const int sw1 = L * 128 + (((4 + H) ^ (L & 7)) << 4);
    const int wm8 = wm * 8192;
    const int wn4 = wn * 4096;

    bf16x8 a0[4][2], a1[4][2], b0[2][2], b1[2][2];
    f32x4 acc[8][4] = {};

    // prologue: tile0 all 4 pieces -> buf0; tile1 {Bh0,Bh1,Ah0} -> buf1
    __builtin_amdgcn_global_load_lds(GAS(pA1), LAS(lds + tid * 16), 16, 0, 0);
    __builtin_amdgcn_global_load_lds(GAS(pA2), LAS(lds + 8192 + tid * 16), 16, 0, 0);
    __builtin_amdgcn_global_load_lds(GAS(pA3), LAS(lds + 16384 + tid * 16), 16, 0, 0);
    __builtin_amdgcn_global_load_lds(GAS(pA4), LAS(lds + 24576 + tid * 16), 16, 0, 0);
    __builtin_amdgcn_global_load_lds(GAS(pB1), LAS(lds + 32768 + tid * 16), 16, 0, 0);
    __builtin_amdgcn_global_load_lds(GAS(pB2), LAS(lds + 40960 + tid * 16), 16, 0, 0);
    __builtin_amdgcn_global_load_lds(GAS(pB3), LAS(lds + 49152 + tid * 16), 16, 0, 0);
    __builtin_amdgcn_global_load_lds(GAS(pB4), LAS(lds + 57344 + tid * 16), 16, 0, 0);
    __builtin_amdgcn_global_load_lds(GAS(pB1 + 64), LAS(lds + 65536 + 32768 + tid * 16), 16, 0, 0);
    __builtin_amdgcn_global_load_lds(GAS(pB2 + 64), LAS(lds + 65536 + 40960 + tid * 16), 16, 0, 0);
    __builtin_amdgcn_global_load_lds(GAS(pB3 + 64), LAS(lds + 65536 + 49152 + tid * 16), 16, 0, 0);
    __builtin_amdgcn_global_load_lds(GAS(pB4 + 64), LAS(lds + 65536 + 57344 + tid * 16), 16, 0, 0);
    __builtin_amdgcn_global_load_lds(GAS(pA1 + 64), LAS(lds + 65536 + tid * 16), 16, 0, 0);
    __builtin_amdgcn_global_load_lds(GAS(pA2 + 64), LAS(lds + 65536 + 8192 + tid * 16), 16, 0, 0);
    WAITV(6);
    BARR();
    // "P3(-1)/P4(-1)" reads: b0(0), a0(0) from buf0
    #pragma unroll
    for (int n = 0; n < 2; n++) {
        b0[n][0] = *(const bf16x8*)(lds + 32768 + wn4 + n * 2048 + sw0);
        b0[n][1] = *(const bf16x8*)(lds + 32768 + wn4 + n * 2048 + sw1);
    }
    #pragma unroll
    for (int m = 0; m < 4; m++) {
        a0[m][0] = *(const bf16x8*)(lds + wm8 + m * 2048 + sw0);
        a0[m][1] = *(const bf16x8*)(lds + wm8 + m * 2048 + sw1);
    }

    #pragma unroll 1
    for (int t = 0; t < 64; t += 2) {
        tile_step<0>(lds, tid, pA1, pA2, pA3, pA4, pB1, pB2, pB3, pB4,
                     ((t + 1) & 63) * 64, ((t + 2) & 63) * 64,
                     wm8, wn4, sw0, sw1, a0, a1, b0, b1, acc);
        tile_step<1>(lds, tid, pA1, pA2, pA3, pA4, pB1, pB2, pB3, pB4,
                     ((t + 2) & 63) * 64, ((t + 3) & 63) * 64,
                     wm8, wn4, sw0, sw1, a0, a1, b0, b1, acc);
    }
    WAITV(0); // drain wrap-around junk prefetches

    // epilogue: out = acc * tmpR (f32). Row/col mapping per wave remap.
    #pragma unroll
    for (int m = 0; m < 8; m++) {
        size_t rbase = brow + (size_t)((m >> 2) * 128 + wm * 64 + (m & 3) * 16 + (H << 2));
        #pragma unroll
        for (int n = 0; n < 4; n++) {
            size_t col = bcol + (size_t)((n >> 1) * 128 + wn * 32 + (n & 1) * 16 + L);
            #pragma unroll
            for (int j = 0; j < 4; j++) {
                size_t idx = (rbase + j) * DOUT + col;
                out[idx] = acc[m][n][j] * (float)tR[idx];
            }
        }
    }
}

// ---------------------------------------------------------------------------
extern "C" void kernel_launch(void* const* d_in, const int* in_sizes, int n_in,
                              void* d_out, int out_size, void* d_ws, size_t ws_size,
                              hipStream_t stream)
{
    (void)in_sizes; (void)n_in; (void)out_size;
    const float* x  = (const float*)d_in[0];
    const float* cl = (const float*)d_in[1];
    const float* W  = (const float*)d_in[2];
    const float* sL = (const float*)d_in[3];
    const float* sR = (const float*)d_in[4];
    float* out = (float*)d_out;

    const size_t AP_BYTES = (size_t)BB * DIN * sizeof(bf16);
    const size_t WT_BYTES = (size_t)DIN * DOUT * sizeof(bf16);
    const size_t TR_BYTES = (size_t)BB * DOUT * sizeof(bf16);
    if (ws_size < AP_BYTES + WT_BYTES + TR_BYTES) return;

    char* ws = (char*)d_ws;
    bf16* Ap = (bf16*)ws;
    bf16* Wt = (bf16*)(ws + AP_BYTES);
    bf16* tR = (bf16*)(ws + AP_BYTES + WT_BYTES);

    prologue_kernel<<<dim3(BB / 128, DIN / 128), 256, 0, stream>>>(x, cl, sL, sR, Ap, tR);
    transpose_kernel<<<dim3(DOUT / 256, DIN / 32), 256, 0, stream>>>(W, Wt);
    gemm_kernel<<<dim3((BB / 256) * (DOUT / 256)), 512, 0, stream>>>(Ap, Wt, tR, out);
}

// Round 4
// 330.640 us; speedup vs baseline: 1.1895x; 1.1895x over previous
//
#include <hip/hip_runtime.h>
#include <cstdint>

// Problem constants (from reference): B=8192, DIN=DOUT=4096, NC=64
#define BB   8192
#define DIN  4096
#define DOUT 4096
#define NCL  64

typedef __bf16 bf16;
typedef __attribute__((ext_vector_type(8))) __bf16 bf16x8;
typedef __attribute__((ext_vector_type(4))) float   f32x4;

#define GAS(p) (reinterpret_cast<uint32_t __attribute__((address_space(1)))*>(reinterpret_cast<uintptr_t>(p)))
#define LAS(p) (reinterpret_cast<uint32_t __attribute__((address_space(3)))*>(reinterpret_cast<uintptr_t>(p)))

#define WAITV(n)  asm volatile("s_waitcnt vmcnt(" #n ")" ::: "memory")
#define WAITL()   asm volatile("s_waitcnt lgkmcnt(0)" ::: "memory")
#define BARR()    __builtin_amdgcn_s_barrier()
#define SCHED0()  __builtin_amdgcn_sched_barrier(0)
#define MFMA(a, b, c) __builtin_amdgcn_mfma_f32_16x16x32_bf16((a), (b), (c), 0, 0, 0)

// ---------------------------------------------------------------------------
// Kernel 1: prologue. tmpL = cluster @ style_L (K=64 MFMA, f32 acc);
// writes A' = bf16(x * tmpL). Blocks with blockIdx.y==0 also dump the
// cluster tile as bf16 row-major (B x 64) for the GEMM's fused-tmpR tile.
// ---------------------------------------------------------------------------
__global__ __launch_bounds__(256) void prologue_kernel(
    const float* __restrict__ x, const float* __restrict__ cl,
    const float* __restrict__ sL, bf16* __restrict__ Ap,
    bf16* __restrict__ clb)
{
    __shared__ uint4 lds_u4[2048]; // 32 KiB
    char* lds = (char*)lds_u4;
    const int t    = threadIdx.x;
    const int lane = t & 63;
    const int w    = t >> 6;
    const int wm   = w >> 1, wn = w & 1;
    const int r0   = blockIdx.x * 128;
    const int c0   = blockIdx.y * 128;

    // stage cluster tile (128x64 f32 -> bf16), swizzled
    #pragma unroll
    for (int i = 0; i < 4; i++) {
        int tk  = t + i * 256;
        int row = tk >> 3, ch = tk & 7;
        const float* src = cl + (size_t)(r0 + row) * NCL + ch * 8;
        float4 v0 = *(const float4*)src;
        float4 v1 = *(const float4*)(src + 4);
        bf16x8 pk;
        pk[0]=(bf16)v0.x; pk[1]=(bf16)v0.y; pk[2]=(bf16)v0.z; pk[3]=(bf16)v0.w;
        pk[4]=(bf16)v1.x; pk[5]=(bf16)v1.y; pk[6]=(bf16)v1.z; pk[7]=(bf16)v1.w;
        *(bf16x8*)(lds + row * 128 + ((ch ^ (row & 7)) << 4)) = pk;
        if (blockIdx.y == 0)
            *(bf16x8*)(clb + (size_t)(r0 + row) * NCL + ch * 8) = pk;
    }
    // stage style_L tile transposed: SL[n][k] = style_L[k][c0+n]
    #pragma unroll
    for (int i = 0; i < 4; i++) {
        int tk = t + i * 256;
        int n  = tk & 127, c = tk >> 7;
        bf16x8 pl;
        #pragma unroll
        for (int j = 0; j < 8; j++)
            pl[j] = (bf16)sL[(size_t)(c * 8 + j) * DIN + c0 + n];
        *(bf16x8*)(lds + 16384 + n * 128 + ((c ^ (n & 7)) << 4)) = pl;
    }
    __syncthreads();

    f32x4 accL[4][4] = {};
    #pragma unroll
    for (int s = 0; s < 2; s++) {
        bf16x8 a[4], bl[4];
        #pragma unroll
        for (int m = 0; m < 4; m++) {
            int row = wm * 64 + m * 16 + (lane & 15);
            int ch  = s * 4 + (lane >> 4);
            a[m] = *(bf16x8*)(lds + row * 128 + ((ch ^ (row & 7)) << 4));
        }
        #pragma unroll
        for (int n = 0; n < 4; n++) {
            int row = wn * 64 + n * 16 + (lane & 15);
            int ch  = s * 4 + (lane >> 4);
            bl[n] = *(bf16x8*)(lds + 16384 + row * 128 + ((ch ^ (row & 7)) << 4));
        }
        #pragma unroll
        for (int m = 0; m < 4; m++)
            #pragma unroll
            for (int n = 0; n < 4; n++)
                accL[m][n] = MFMA(a[m], bl[n], accL[m][n]);
    }

    // A' = bf16(x * tmpL);  C/D layout: col=lane&15, row=(lane>>4)*4+j
    #pragma unroll
    for (int m = 0; m < 4; m++) {
        int rbase = r0 + wm * 64 + m * 16 + ((lane >> 4) << 2);
        #pragma unroll
        for (int n = 0; n < 4; n++) {
            int col = c0 + wn * 64 + n * 16 + (lane & 15);
            #pragma unroll
            for (int j = 0; j < 4; j++) {
                size_t idx = (size_t)(rbase + j) * DIN + col;
                Ap[idx] = (bf16)(x[idx] * accL[m][n][j]);
            }
        }
    }
}

// ---------------------------------------------------------------------------
// Kernel 2: W (DIN x DOUT f32) -> Wt (DOUT x DIN bf16)  (unchanged)
// ---------------------------------------------------------------------------
__global__ __launch_bounds__(256) void transpose_kernel(
    const float* __restrict__ W, bf16* __restrict__ Wt)
{
    const int t  = threadIdx.x;
    const int n  = blockIdx.x * 256 + t;
    const int k0 = blockIdx.y * 32;
    bf16x8 v[4];
    #pragma unroll
    for (int q = 0; q < 4; q++)
        #pragma unroll
        for (int j = 0; j < 8; j++)
            v[q][j] = (bf16)W[(size_t)(k0 + q * 8 + j) * DOUT + n];
    bf16* dst = Wt + (size_t)n * DIN + k0;
    #pragma unroll
    for (int q = 0; q < 4; q++)
        *(bf16x8*)(dst + q * 8) = v[q];
}

// ---------------------------------------------------------------------------
// Kernel 2b: style_R (64 x DOUT f32) -> sRt (DOUT x 64 bf16)
// ---------------------------------------------------------------------------
__global__ __launch_bounds__(256) void srt_kernel(
    const float* __restrict__ sR, bf16* __restrict__ srt)
{
    const int o = blockIdx.x * 256 + threadIdx.x; // 0..4095
    bf16x8 v[8];
    #pragma unroll
    for (int q = 0; q < 8; q++)
        #pragma unroll
        for (int j = 0; j < 8; j++)
            v[q][j] = (bf16)sR[(size_t)(q * 8 + j) * DOUT + o];
    bf16* dst = srt + (size_t)o * 64;
    #pragma unroll
    for (int q = 0; q < 8; q++)
        *(bf16x8*)(dst + q * 8) = v[q];
}

// ---------------------------------------------------------------------------
// Kernel 3: 256x256-tile 8-phase GEMM (R2 schedule, k-reordered MFMA) with
// FUSED tmpR: after the K=4096 main loop, one extra K=64 MFMA tile computes
// tmpR(256x256) from cluster_bf16 (A) and sRt (B) into temp accumulators and
// multiplies element-wise into acc (identical C/D fragment layout).
// Schedule per K-tile t (CB = buf[t&1], OB = other), vmcnt(6) once per tile:
//   P1: ds_read all A-quad0 + all B (16); stage (t+1).Ah1->OB; BAR; lgkm0;
//       MFMA Q(a,b0..1); BAR
//   P2: stage (t+2).Bh0->CB; BAR; MFMA Q(a,b2..3); BAR
//   P3: ds_read A-quad1 (8); stage (t+2).Bh1->CB; BAR; lgkm0; MFMA; BAR
//   P4: stage (t+2).Ah0->CB; BAR; MFMA; vmcnt(6); BAR
// ---------------------------------------------------------------------------
template<int CUR>
__device__ __forceinline__ void tile_step(char* lds, int tid,
    const bf16* pA1, const bf16* pA2, const bf16* pA3, const bf16* pA4,
    const bf16* pB1, const bf16* pB2, const bf16* pB3, const bf16* pB4,
    int kA1, int kA2, int aoff0, int aoff1, int boff0, int boff1,
    bf16x8 a[4][2], bf16x8 b[4][2], f32x4 acc[8][4])
{
    constexpr int CB = CUR * 65536;
    constexpr int OB = (CUR ^ 1) * 65536;

    // ---------- P1 ----------
    #pragma unroll
    for (int mq = 0; mq < 4; ++mq) {
        a[mq][0] = *(const bf16x8*)(lds + CB + mq * 2048 + aoff0);
        a[mq][1] = *(const bf16x8*)(lds + CB + mq * 2048 + aoff1);
    }
    #pragma unroll
    for (int nb = 0; nb < 4; ++nb) {
        b[nb][0] = *(const bf16x8*)(lds + CB + nb * 2048 + boff0);
        b[nb][1] = *(const bf16x8*)(lds + CB + nb * 2048 + boff1);
    }
    __builtin_amdgcn_global_load_lds(GAS(pA3 + kA1), LAS(lds + OB + 16384 + tid * 16), 16, 0, 0);
    __builtin_amdgcn_global_load_lds(GAS(pA4 + kA1), LAS(lds + OB + 24576 + tid * 16), 16, 0, 0);
    BARR();
    WAITL(); SCHED0();
    __builtin_amdgcn_s_setprio(1);
    #pragma unroll
    for (int k = 0; k < 2; ++k)
        #pragma unroll
        for (int mq = 0; mq < 4; ++mq)
            #pragma unroll
            for (int nq = 0; nq < 2; ++nq)
                acc[mq][nq] = MFMA(a[mq][k], b[nq][k], acc[mq][nq]);
    __builtin_amdgcn_s_setprio(0);
    BARR();

    // ---------- P2 ----------
    __builtin_amdgcn_global_load_lds(GAS(pB1 + kA2), LAS(lds + CB + 32768 + tid * 16), 16, 0, 0);
    __builtin_amdgcn_global_load_lds(GAS(pB2 + kA2), LAS(lds + CB + 40960 + tid * 16), 16, 0, 0);
    BARR();
    __builtin_amdgcn_s_setprio(1);
    #pragma unroll
    for (int k = 0; k < 2; ++k)
        #pragma unroll
        for (int mq = 0; mq < 4; ++mq)
            #pragma unroll
            for (int nq = 0; nq < 2; ++nq)
                acc[mq][2 + nq] = MFMA(a[mq][k], b[2 + nq][k], acc[mq][2 + nq]);
    __builtin_amdgcn_s_setprio(0);
    BARR();

    // ---------- P3 ----------
    #pragma unroll
    for (int mq = 0; mq < 4; ++mq) {
        a[mq][0] = *(const bf16x8*)(lds + CB + 8192 + mq * 2048 + aoff0);
        a[mq][1] = *(const bf16x8*)(lds + CB + 8192 + mq * 2048 + aoff1);
    }
    __builtin_amdgcn_global_load_lds(GAS(pB3 + kA2), LAS(lds + CB + 49152 + tid * 16), 16, 0, 0);
    __builtin_amdgcn_global_load_lds(GAS(pB4 + kA2), LAS(lds + CB + 57344 + tid * 16), 16, 0, 0);
    BARR();
    WAITL(); SCHED0();
    __builtin_amdgcn_s_setprio(1);
    #pragma unroll
    for (int k = 0; k < 2; ++k)
        #pragma unroll
        for (int mq = 0; mq < 4; ++mq)
            #pragma unroll
            for (int nq = 0; nq < 2; ++nq)
                acc[4 + mq][2 + nq] = MFMA(a[mq][k], b[2 + nq][k], acc[4 + mq][2 + nq]);
    __builtin_amdgcn_s_setprio(0);
    BARR();

    // ---------- P4 ----------
    __builtin_amdgcn_global_load_lds(GAS(pA1 + kA2), LAS(lds + CB + tid * 16), 16, 0, 0);
    __builtin_amdgcn_global_load_lds(GAS(pA2 + kA2), LAS(lds + CB + 8192 + tid * 16), 16, 0, 0);
    BARR();
    __builtin_amdgcn_s_setprio(1);
    #pragma unroll
    for (int k = 0; k < 2; ++k)
        #pragma unroll
        for (int mq = 0; mq < 4; ++mq)
            #pragma unroll
            for (int nq = 0; nq < 2; ++nq)
                acc[4 + mq][nq] = MFMA(a[mq][k], b[nq][k], acc[4 + mq][nq]);
    __builtin_amdgcn_s_setprio(0);
    WAITV(6);
    BARR();
}

__global__ __launch_bounds__(512, 2) void gemm_kernel(
    const bf16* __restrict__ Ap, const bf16* __restrict__ Wt,
    const bf16* __restrict__ clb, const bf16* __restrict__ srt,
    float* __restrict__ out)
{
    __shared__ uint4 smem[8192]; // 128 KiB
    char* lds = (char*)smem;
    const int tid  = threadIdx.x;
    const int lane = tid & 63;
    const int w    = tid >> 6;
    const int wm   = w >> 2;   // 0..1
    const int wn   = w & 3;    // 0..3
    const int L = lane & 15, H = lane >> 4;

    // XCD-bijective swizzle: 512 blocks, 8 XCDs, 64 tiles each (4 mt x 16 nt)
    const int bid = blockIdx.x;
    const int xc  = bid & 7, ii = bid >> 3;
    const int mt  = xc * 4 + (ii >> 4);
    const int nt  = ii & 15;
    const size_t brow = (size_t)mt * 256;
    const size_t bcol = (size_t)nt * 256;

    // staging: dest linear (tid*16), source chunk inverse-swizzled
    const int r1  = tid >> 3;
    const int gch = (tid & 7) ^ (r1 & 7);
    const bf16* pA1 = Ap + (brow + r1) * (size_t)DIN + gch * 8;
    const bf16* pA2 = pA1 + (size_t)64  * DIN;
    const bf16* pA3 = pA1 + (size_t)128 * DIN;
    const bf16* pA4 = pA1 + (size_t)192 * DIN;
    const bf16* pB1 = Wt + (bcol + r1) * (size_t)DIN + gch * 8;
    const bf16* pB2 = pB1 + (size_t)64  * DIN;
    const bf16* pB3 = pB1 + (size_t)128 * DIN;
    const bf16* pB4 = pB1 + (size_t)192 * DIN;

    // fragment ds_read offsets: chunk = kk*4+H, slot = chunk^(L&7)
    const int swz0 = (H ^ (L & 7)) << 4;
    const int swz1 = ((4 + H) ^ (L & 7)) << 4;
    const int aoff0 = wm * 16384 + L * 128 + swz0;
    const int aoff1 = wm * 16384 + L * 128 + swz1;
    const int boff0 = 32768 + (wn >> 1) * 16384 + (wn & 1) * 8192 + L * 128 + swz0;
    const int boff1 = 32768 + (wn >> 1) * 16384 + (wn & 1) * 8192 + L * 128 + swz1;

    bf16x8 a[4][2], b[4][2];
    f32x4 acc[8][4] = {};

    // prologue: tile0 all 4 pieces -> buf0; tile1 {Bh0,Bh1,Ah0} -> buf1
    __builtin_amdgcn_global_load_lds(GAS(pA1), LAS(lds + tid * 16), 16, 0, 0);
    __builtin_amdgcn_global_load_lds(GAS(pA2), LAS(lds + 8192 + tid * 16), 16, 0, 0);
    __builtin_amdgcn_global_load_lds(GAS(pA3), LAS(lds + 16384 + tid * 16), 16, 0, 0);
    __builtin_amdgcn_global_load_lds(GAS(pA4), LAS(lds + 24576 + tid * 16), 16, 0, 0);
    __builtin_amdgcn_global_load_lds(GAS(pB1), LAS(lds + 32768 + tid * 16), 16, 0, 0);
    __builtin_amdgcn_global_load_lds(GAS(pB2), LAS(lds + 40960 + tid * 16), 16, 0, 0);
    __builtin_amdgcn_global_load_lds(GAS(pB3), LAS(lds + 49152 + tid * 16), 16, 0, 0);
    __builtin_amdgcn_global_load_lds(GAS(pB4), LAS(lds + 57344 + tid * 16), 16, 0, 0);
    __builtin_amdgcn_global_load_lds(GAS(pB1 + 64), LAS(lds + 65536 + 32768 + tid * 16), 16, 0, 0);
    __builtin_amdgcn_global_load_lds(GAS(pB2 + 64), LAS(lds + 65536 + 40960 + tid * 16), 16, 0, 0);
    __builtin_amdgcn_global_load_lds(GAS(pB3 + 64), LAS(lds + 65536 + 49152 + tid * 16), 16, 0, 0);
    __builtin_amdgcn_global_load_lds(GAS(pB4 + 64), LAS(lds + 65536 + 57344 + tid * 16), 16, 0, 0);
    __builtin_amdgcn_global_load_lds(GAS(pA1 + 64), LAS(lds + 65536 + tid * 16), 16, 0, 0);
    __builtin_amdgcn_global_load_lds(GAS(pA2 + 64), LAS(lds + 65536 + 8192 + tid * 16), 16, 0, 0);
    WAITV(6);
    BARR();

    #pragma unroll 1
    for (int t = 0; t < 64; t += 2) {
        tile_step<0>(lds, tid, pA1, pA2, pA3, pA4, pB1, pB2, pB3, pB4,
                     ((t + 1) & 63) * 64, ((t + 2) & 63) * 64,
                     aoff0, aoff1, boff0, boff1, a, b, acc);
        tile_step<1>(lds, tid, pA1, pA2, pA3, pA4, pB1, pB2, pB3, pB4,
                     ((t + 2) & 63) * 64, ((t + 3) & 63) * 64,
                     aoff0, aoff1, boff0, boff1, a, b, acc);
    }

    // ---- fused tmpR tile: acc *= (cluster @ style_R) over K=64 ----
    WAITV(0);                    // drain wrap-around junk prefetches (same LDS slots)
    const bf16* pC = clb + (brow + r1) * 64 + gch * 8;
    const bf16* pR = srt + (bcol + r1) * 64 + gch * 8;
    __builtin_amdgcn_global_load_lds(GAS(pC),         LAS(lds + tid * 16), 16, 0, 0);
    __builtin_amdgcn_global_load_lds(GAS(pC + 4096),  LAS(lds + 8192 + tid * 16), 16, 0, 0);
    __builtin_amdgcn_global_load_lds(GAS(pC + 8192),  LAS(lds + 16384 + tid * 16), 16, 0, 0);
    __builtin_amdgcn_global_load_lds(GAS(pC + 12288), LAS(lds + 24576 + tid * 16), 16, 0, 0);
    __builtin_amdgcn_global_load_lds(GAS(pR),         LAS(lds + 32768 + tid * 16), 16, 0, 0);
    __builtin_amdgcn_global_load_lds(GAS(pR + 4096),  LAS(lds + 40960 + tid * 16), 16, 0, 0);
    __builtin_amdgcn_global_load_lds(GAS(pR + 8192),  LAS(lds + 49152 + tid * 16), 16, 0, 0);
    __builtin_amdgcn_global_load_lds(GAS(pR + 12288), LAS(lds + 57344 + tid * 16), 16, 0, 0);
    WAITV(0);
    BARR();

    #pragma unroll
    for (int nb = 0; nb < 4; ++nb) {
        b[nb][0] = *(const bf16x8*)(lds + nb * 2048 + boff0);
        b[nb][1] = *(const bf16x8*)(lds + nb * 2048 + boff1);
    }
    #pragma unroll
    for (int half = 0; half < 2; ++half) {
        #pragma unroll
        for (int mq = 0; mq < 4; ++mq) {
            a[mq][0] = *(const bf16x8*)(lds + half * 8192 + mq * 2048 + aoff0);
            a[mq][1] = *(const bf16x8*)(lds + half * 8192 + mq * 2048 + aoff1);
        }
        WAITL(); SCHED0();
        f32x4 r4[4][4] = {};
        #pragma unroll
        for (int k = 0; k < 2; ++k)
            #pragma unroll
            for (int mq = 0; mq < 4; ++mq)
                #pragma unroll
                for (int nb = 0; nb < 4; ++nb)
                    r4[mq][nb] = MFMA(a[mq][k], b[nb][k], r4[mq][nb]);
        #pragma unroll
        for (int mq = 0; mq < 4; ++mq)
            #pragma unroll
            for (int nb = 0; nb < 4; ++nb)
                acc[half * 4 + mq][nb] *= r4[mq][nb];
    }

    // epilogue: out = acc (already modulated), f32 stores
    #pragma unroll
    for (int m = 0; m < 8; m++) {
        size_t rbase = brow + (size_t)(wm * 128 + m * 16 + (H << 2));
        #pragma unroll
        for (int n = 0; n < 4; n++) {
            size_t col = bcol + (size_t)(wn * 64 + n * 16 + L);
            #pragma unroll
            for (int j = 0; j < 4; j++) {
                size_t idx = (rbase + j) * DOUT + col;
                out[idx] = acc[m][n][j];
            }
        }
    }
}

// ---------------------------------------------------------------------------
extern "C" void kernel_launch(void* const* d_in, const int* in_sizes, int n_in,
                              void* d_out, int out_size, void* d_ws, size_t ws_size,
                              hipStream_t stream)
{
    (void)in_sizes; (void)n_in; (void)out_size;
    const float* x  = (const float*)d_in[0];
    const float* cl = (const float*)d_in[1];
    const float* W  = (const float*)d_in[2];
    const float* sL = (const float*)d_in[3];
    const float* sR = (const float*)d_in[4];
    float* out = (float*)d_out;

    // ws: A' (64MiB) | Wt (32MiB) | clb (1MiB) | srt (0.5MiB)
    const size_t AP_BYTES = (size_t)BB * DIN * sizeof(bf16);
    const size_t WT_BYTES = (size_t)DIN * DOUT * sizeof(bf16);
    const size_t CL_BYTES = (size_t)BB * NCL * sizeof(bf16);
    const size_t SR_BYTES = (size_t)DOUT * NCL * sizeof(bf16);
    if (ws_size < AP_BYTES + WT_BYTES + CL_BYTES + SR_BYTES) return;

    char* ws = (char*)d_ws;
    bf16* Ap  = (bf16*)ws;
    bf16* Wt  = (bf16*)(ws + AP_BYTES);
    bf16* clb = (bf16*)(ws + AP_BYTES + WT_BYTES);
    bf16* srt = (bf16*)(ws + AP_BYTES + WT_BYTES + CL_BYTES);

    prologue_kernel<<<dim3(BB / 128, DIN / 128), 256, 0, stream>>>(x, cl, sL, Ap, clb);
    transpose_kernel<<<dim3(DOUT / 256, DIN / 32), 256, 0, stream>>>(W, Wt);
    srt_kernel<<<dim3(DOUT / 256), 256, 0, stream>>>(sR, srt);
    gemm_kernel<<<dim3((BB / 256) * (DOUT / 256)), 512, 0, stream>>>(Ap, Wt, clb, srt, out);
}